// Round 1
// baseline (634.281 us; speedup 1.0000x reference)
//
#include <hip/hip_runtime.h>

// Problem constants (match reference file)
#define B_ 16
#define N_ 8192
#define M_ 2048
#define K_ 32
#define C_ 128

// out layout: pts [B,M,K,3] floats, then features [B,M,K,C] floats
#define PTS_ELEMS ((size_t)B_ * M_ * K_ * 3)   // 3,145,728

// One thread per (b,m,k). K=32 groups align to 32-lane halves of a wave64,
// so max-over-K is a 5-step shuffle butterfly (xor masks 1..16 stay in-group).
__global__ void pts_kernel(const float* __restrict__ points,
                           const float* __restrict__ next_pts,
                           const int* __restrict__ indices,
                           float* __restrict__ out_pts) {
    int t = blockIdx.x * blockDim.x + threadIdx.x;   // flat over B*M*K
    // decompose: t = ((b*M + m)*K + k)
    int bm = t >> 5;              // / K_
    int m  = bm & (M_ - 1);
    int b  = bm >> 11;            // / M_

    int idx = indices[t];
    const float* p  = points   + ((size_t)b * N_ + idx) * 3;
    const float* nq = next_pts + ((size_t)b * M_ + m) * 3;

    float x = p[0] - nq[0];
    float y = p[1] - nq[1];
    float z = p[2] - nq[2];
    float sq = x * x + y * y + z * z;

    // max over the K=32 group (lanes 0-31 / 32-63 are distinct groups)
    float mx = sq;
    #pragma unroll
    for (int off = 1; off <= 16; off <<= 1) {
        float o = __shfl_xor(mx, off, 64);
        mx = fmaxf(mx, o);
    }
    float maxi = sqrtf(mx);
    if (maxi == 0.0f) maxi = 1.0f;

    float* o = out_pts + (size_t)t * 3;
    o[0] = x / maxi;
    o[1] = y / maxi;
    o[2] = z / maxi;
}

// One thread per float4 of the feature output. 32 consecutive threads share
// one source row (contiguous 512B read from input), writes fully coalesced.
__global__ void feat_kernel(const float* __restrict__ input,
                            const int* __restrict__ indices,
                            float4* __restrict__ out_feat) {
    size_t f = (size_t)blockIdx.x * blockDim.x + threadIdx.x; // B*M*K*(C/4)
    int c4 = (int)(f & 31);           // C/4 = 32
    size_t row = f >> 5;              // (b*M + m)*K + k
    int b = (int)(row >> 16);         // / (M_*K_) = 65536

    int idx = indices[row];
    const float4* src = (const float4*)(input + ((size_t)b * N_ + idx) * C_);
    out_feat[f] = src[c4];
}

extern "C" void kernel_launch(void* const* d_in, const int* in_sizes, int n_in,
                              void* d_out, int out_size, void* d_ws, size_t ws_size,
                              hipStream_t stream) {
    const float* input    = (const float*)d_in[0];
    const float* points   = (const float*)d_in[1];
    const float* next_pts = (const float*)d_in[2];
    const int*   indices  = (const int*)d_in[3];
    float* out = (float*)d_out;

    float* out_pts  = out;
    float4* out_feat = (float4*)(out + PTS_ELEMS);  // 12.58 MB offset, 16B aligned

    // pts: B*M*K = 1,048,576 threads
    {
        int total = B_ * M_ * K_;
        int block = 256;
        int grid = total / block;   // 4096
        pts_kernel<<<grid, block, 0, stream>>>(points, next_pts, indices, out_pts);
    }
    // features: B*M*K*(C/4) = 33,554,432 threads
    {
        size_t total = (size_t)B_ * M_ * K_ * (C_ / 4);
        int block = 256;
        int grid = (int)(total / block);  // 131,072
        feat_kernel<<<grid, block, 0, stream>>>(input, indices, out_feat);
    }
}